// Round 16
// baseline (108.507 us; speedup 1.0000x reference)
//
#include <hip/hip_runtime.h>
#include <math.h>

#define T_LEN 4096
#define NF 60
#define NBINS 33
#define KPAD 2048
#define HID 256
#define NTOK 16384
#define LINE 4208    // reflected line length (covers staging slop, mult of 8)

typedef _Float16 half_t;
typedef half_t half8 __attribute__((ext_vector_type(8)));
typedef half_t half4 __attribute__((ext_vector_type(4)));
typedef float f32x4 __attribute__((ext_vector_type(4)));

// ---------- compile-time cos table: cos(2*pi*j/64), j=0..63 ----------
constexpr double K_PI = 3.14159265358979323846;
constexpr double tcos(double x) {
    while (x >  K_PI) x -= 2.0 * K_PI;
    while (x < -K_PI) x += 2.0 * K_PI;
    double x2 = x * x, s = 0.0, term = 1.0;
    for (int m = 0; m < 14; ++m) { s += term; term *= -x2 / ((2.0*m + 1.0) * (2.0*m + 2.0)); }
    return s;
}
struct CosTab { float v[64]; };
constexpr CosTab make_tab() {
    CosTab t{};
    for (int j = 0; j < 64; ++j) t.v[j] = (float)tcos(2.0 * K_PI * (double)j / 64.0);
    return t;
}
__device__ constexpr CosTab CTd = make_tab();

// stored fft feature = log2(1+mag); the *ln2 is folded into W1T rows.
__device__ __forceinline__ float log2_1p(float x) {
    return __log2f(1.0f + x);
}

// ---------- one-time prep: fp16 DFT table + fp16 transposed weights ----------
// k-layout: [0,1920) bins (f=k>>5, bin=k&31); [1920,1980) raw; [1980,2040)
// bin32 of f=k-1980; [2040,2048) zero.  FFT-feature rows scaled by ln2.
__global__ __launch_bounds__(256) void prep_kernel(
        const float* __restrict__ W1, const float* __restrict__ W2,
        const float* __restrict__ W3,
        half_t* __restrict__ dftH,
        half_t* __restrict__ W1T, half_t* __restrict__ W2T,
        half_t* __restrict__ W3T) {
    int i = blockIdx.x * 256 + threadIdx.x;
    if (i < 4096) {
        int row = i >> 6, n = i & 63;
        float c = (row < 33) ? CTd.v[(row * n) & 63]
                             : CTd.v[((row - 32) * n + 48) & 63];
        dftH[i] = (half_t)c;
        return;
    }
    i -= 4096;
    if (i < 256 * KPAD) {
        int gk = i & (KPAD - 1);
        float v = 0.f;
        if (gk < 2040) {
            int j = i >> 11;
            int r;
            bool isfft = true;
            if (gk < 1920) {
                int f = gk >> 5, bin = gk & 31;
                r = NF + f * NBINS + bin;                 // bins 0..31
            } else if (gk < 1980) {
                r = gk - 1920; isfft = false;             // raw feature
            } else {
                r = NF + (gk - 1980) * NBINS + 32;        // bin 32
            }
            v = W1[(size_t)r * HID + j];
            if (isfft) v *= 0.69314718055994531f;         // ln2 fold
        }
        W1T[i] = (half_t)v;
        return;
    }
    i -= 256 * KPAD;
    if (i < 256 * 256) {
        int k = i & 255, j = i >> 8;
        W2T[i] = (half_t)W2[(size_t)k * HID + j];
        return;
    }
    i -= 256 * 256;
    if (i < 128 * 256) {
        int k = i & 255, j = i >> 8;
        W3T[i] = (half_t)W3[(size_t)k * 128 + j];
    }
}

// ---------- merged: reflected lines (blocks 0..239) + raw feats (240..303) --
__global__ __launch_bounds__(256) void xr_kernel(
        const float* __restrict__ x, half_t* __restrict__ lineG,
        half_t* __restrict__ H0) {
    if (blockIdx.x < 240) {
        const int bf = blockIdx.x;
        const int b = bf / NF, f = bf - b * NF;
        const float* xb = x + (size_t)b * T_LEN * NF + f;
        half_t* L = lineG + (size_t)bf * LINE;
        for (int j = threadIdx.x; j < LINE; j += 256) {
            int s = j - 32;
            int r = (s < 0) ? -s : ((s > T_LEN - 1) ? 2 * (T_LEN - 1) - s : s);
            L[j] = (half_t)xb[(size_t)r * NF];
        }
        return;
    }
    const int t = (blockIdx.x - 240) * 256 + threadIdx.x;
    const int b = t >> 12, tl = t & (T_LEN - 1);
    const int i = (b << 12) + ((tl & 7) << 9) + (tl >> 3);
    const float* xp = x + (size_t)t * NF;
    half_t* hp = H0 + (size_t)i * KPAD;
#pragma unroll
    for (int f4 = 0; f4 < 15; ++f4) {
        float4 v = *(const float4*)(xp + f4 * 4);
        half4 h;
        h[0] = (half_t)v.x; h[1] = (half_t)v.y;
        h[2] = (half_t)v.z; h[3] = (half_t)v.w;
        *(half4*)&hp[1920 + f4 * 4] = h;
    }
    half8 z = {};
    *(half8*)&hp[2040] = z;
}

// ---------- Hankel-DFT via MFMA: block = (b,f,phase c); ILP-pipelined ------
__global__ __launch_bounds__(256) void fft_hankel(
        const half_t* __restrict__ lineG, const half_t* __restrict__ dftH,
        half_t* __restrict__ H0) {
    __shared__ half_t L[4160];   // full c-shifted line (8.3 KB)

    const int bid = blockIdx.x;        // 0..1919
    const int bf = bid >> 3, c = bid & 7;
    const int b = bf / NF, f = bf - b * NF;
    const int tid = threadIdx.x;
    const int lane = tid & 63, wv = tid >> 6;
    const int lr = lane & 15, lg = lane >> 4;

    half8 a[4][2];
#pragma unroll
    for (int rf = 0; rf < 4; ++rf)
#pragma unroll
        for (int ks = 0; ks < 2; ++ks)
            a[rf][ks] = *(const half8*)&dftH[(16 * rf + lr) * 64 + ks * 32 + lg * 8];

    {
        const half_t* src = lineG + (size_t)bf * LINE + c;
        for (int j = tid; j < 4152; j += 256) L[j] = src[j];
    }
    __syncthreads();

    const int i0 = (b << 12) + (c << 9);    // H0 row base
    const int sl = wv * 128 + lr;           // this thread's s for cs=0

    half8 w0 = *(const half8*)&L[8 * sl + lg * 8];
    half8 w1 = *(const half8*)&L[8 * sl + 32 + lg * 8];

#pragma unroll
    for (int cs = 0; cs < 8; ++cs) {
        f32x4 dacc[4] = {};
#pragma unroll
        for (int rf = 0; rf < 4; ++rf)
            dacc[rf] = __builtin_amdgcn_mfma_f32_16x16x32_f16(a[rf][0], w0, dacc[rf], 0, 0, 0);
#pragma unroll
        for (int rf = 0; rf < 4; ++rf)
            dacc[rf] = __builtin_amdgcn_mfma_f32_16x16x32_f16(a[rf][1], w1, dacc[rf], 0, 0, 0);

        if (cs < 7) {   // prefetch next chunk's B-frags (hidden under epilogue)
            const int sn = sl + (cs + 1) * 16;
            w0 = *(const half8*)&L[8 * sn + lg * 8];
            w1 = *(const half8*)&L[8 * sn + 32 + lg * 8];
        }

        half_t* base = H0 + (size_t)(i0 + sl + cs * 16) * KPAD;
#pragma unroll
        for (int rf = 0; rf < 2; ++rf) {
            half4 h4;
#pragma unroll
            for (int r = 0; r < 4; ++r) {
                float re = dacc[rf][r];
                float im = dacc[rf + 2][r];
                float v = (rf == 0 && r == 0)
                    ? ((lg == 0) ? log2_1p(fabsf(re))                 // bin 0
                                 : log2_1p(sqrtf(re * re + im * im)))
                    : log2_1p(sqrtf(re * re + im * im));
                h4[r] = (half_t)v;
            }
            *(half4*)&base[f * 32 + 16 * rf + 4 * lg] = h4;
        }
        if (lg == 0)   // bin 32 = |re_32| (row 32 = rf2 reg0)
            base[1980 + f] = (half_t)log2_1p(fabsf(dacc[2][0]));
    }
}

// ---------- fp16 MFMA GEMM, software-pipelined (layers 1,2) ----------
// BM=64. A: LDS dbuf, 3-deep reg prefetch, XOR-swizzled granules (<=2-way).
// B: direct from L2, 2-deep reg double-buffer. ONE barrier per K-step.
template<int BN>
__global__ __launch_bounds__(256, 4) void gemm_pipe(
        const half_t* __restrict__ A, int lda,
        const half_t* __restrict__ BT, int ldb,
        const float* __restrict__ bias,
        half_t* __restrict__ Ch, int N, int K) {
    constexpr int NFR = BN / 64;
    __shared__ half_t As[2][64 * 64];     // 16 KB, swizzled granules

    const int tid  = threadIdx.x;
    const int row0 = blockIdx.x * 64;
    const int col0 = blockIdx.y * BN;
    const int wv = tid >> 6, lane = tid & 63;
    const int lr = lane & 15, lg = lane >> 4;

    const int srow = tid >> 2, sg = (tid & 3) * 2;
    const int wo0 = srow * 64 + ((sg ^ (srow & 7)) * 8);
    const int wo1 = srow * 64 + (((sg + 1) ^ (srow & 7)) * 8);
    const half_t* ap = A + (size_t)(row0 + srow) * lda + sg * 8;

    const half_t* bp[NFR];
#pragma unroll
    for (int nf = 0; nf < NFR; ++nf)
        bp[nf] = BT + (size_t)(col0 + wv * (16 * NFR) + nf * 16 + lr) * ldb + lg * 8;

    f32x4 acc[4][NFR] = {};
    const int NIT = K / 64;   // even

    half8 bcur[2][NFR], bnxt[2][NFR];
    half8 pa0, pa1, pb0, pb1;

    {
        half8 v0 = *(const half8*)(ap);
        half8 v1 = *(const half8*)(ap + 8);
        *(half8*)&As[0][wo0] = v0;
        *(half8*)&As[0][wo1] = v1;
    }
    if (NIT > 1) { pa0 = *(const half8*)(ap + 64);  pa1 = *(const half8*)(ap + 72); }
    if (NIT > 2) { pb0 = *(const half8*)(ap + 128); pb1 = *(const half8*)(ap + 136); }
#pragma unroll
    for (int ks = 0; ks < 2; ++ks)
#pragma unroll
        for (int nf = 0; nf < NFR; ++nf)
            bcur[ks][nf] = *(const half8*)(bp[nf] + ks * 32);

    for (int it = 0; it < NIT; it += 2) {
        __syncthreads();
        if (it + 1 < NIT) {
#pragma unroll
            for (int ks = 0; ks < 2; ++ks)
#pragma unroll
                for (int nf = 0; nf < NFR; ++nf)
                    bnxt[ks][nf] = *(const half8*)(bp[nf] + (it + 1) * 64 + ks * 32);
        }
#pragma unroll
        for (int ks = 0; ks < 2; ++ks) {
            half8 af[4];
#pragma unroll
            for (int mf = 0; mf < 4; ++mf)
                af[mf] = *(const half8*)&As[0][(mf * 16 + lr) * 64 + (((ks * 4 + lg) ^ (lr & 7)) * 8)];
#pragma unroll
            for (int mf = 0; mf < 4; ++mf)
#pragma unroll
                for (int nf = 0; nf < NFR; ++nf)
                    acc[mf][nf] = __builtin_amdgcn_mfma_f32_16x16x32_f16(af[mf], bcur[ks][nf], acc[mf][nf], 0, 0, 0);
        }
        if (it + 1 < NIT) { *(half8*)&As[1][wo0] = pa0; *(half8*)&As[1][wo1] = pa1; }
        if (it + 3 < NIT) { pa0 = *(const half8*)(ap + (it + 3) * 64); pa1 = *(const half8*)(ap + (it + 3) * 64 + 8); }
        if (it + 1 >= NIT) break;

        __syncthreads();
        if (it + 2 < NIT) {
#pragma unroll
            for (int ks = 0; ks < 2; ++ks)
#pragma unroll
                for (int nf = 0; nf < NFR; ++nf)
                    bcur[ks][nf] = *(const half8*)(bp[nf] + (it + 2) * 64 + ks * 32);
        }
#pragma unroll
        for (int ks = 0; ks < 2; ++ks) {
            half8 af[4];
#pragma unroll
            for (int mf = 0; mf < 4; ++mf)
                af[mf] = *(const half8*)&As[1][(mf * 16 + lr) * 64 + (((ks * 4 + lg) ^ (lr & 7)) * 8)];
#pragma unroll
            for (int mf = 0; mf < 4; ++mf)
#pragma unroll
                for (int nf = 0; nf < NFR; ++nf)
                    acc[mf][nf] = __builtin_amdgcn_mfma_f32_16x16x32_f16(af[mf], bnxt[ks][nf], acc[mf][nf], 0, 0, 0);
        }
        if (it + 2 < NIT) { *(half8*)&As[0][wo0] = pb0; *(half8*)&As[0][wo1] = pb1; }
        if (it + 4 < NIT) { pb0 = *(const half8*)(ap + (it + 4) * 64); pb1 = *(const half8*)(ap + (it + 4) * 64 + 8); }
    }

#pragma unroll
    for (int nf = 0; nf < NFR; ++nf) {
        int col = col0 + wv * (16 * NFR) + nf * 16 + lr;
        float bs = bias[col];
#pragma unroll
        for (int mf = 0; mf < 4; ++mf)
#pragma unroll
            for (int r = 0; r < 4; ++r) {
                int row = row0 + mf * 16 + lg * 4 + r;
                Ch[(size_t)row * N + col] = (half_t)fmaxf(acc[mf][nf][r] + bs, 0.f);
            }
    }
}

// ---------- GEMM3 + head fused: H2[64rows] @ W3 -> LDS -> @ W4 -> out ------
__global__ __launch_bounds__(256) void gemm3_head(
        const half_t* __restrict__ A, const half_t* __restrict__ BT,
        const float* __restrict__ b3, const float* __restrict__ W4,
        const float* __restrict__ b4, float* __restrict__ out) {
    constexpr int NFR = 2, NIT = 4;
    __shared__ half_t As[2][64 * 64];     // 16 KB
    __shared__ float Hs[64][132];         // 33.8 KB (pad 4)
    __shared__ float W4s[384];

    const int tid  = threadIdx.x;
    const int row0 = blockIdx.x * 64;
    const int wv = tid >> 6, lane = tid & 63;
    const int lr = lane & 15, lg = lane >> 4;

    for (int i = tid; i < 384; i += 256) W4s[i] = W4[i];

    const int srow = tid >> 2, sg = (tid & 3) * 2;
    const int wo0 = srow * 64 + ((sg ^ (srow & 7)) * 8);
    const int wo1 = srow * 64 + (((sg + 1) ^ (srow & 7)) * 8);
    const half_t* ap = A + (size_t)(row0 + srow) * 256 + sg * 8;

    const half_t* bp[NFR];
#pragma unroll
    for (int nf = 0; nf < NFR; ++nf)
        bp[nf] = BT + (size_t)(wv * 32 + nf * 16 + lr) * 256 + lg * 8;

    f32x4 acc[4][NFR] = {};
    half8 bcur[2][NFR], bnxt[2][NFR];
    half8 pa0, pa1, pb0, pb1;

    {
        half8 v0 = *(const half8*)(ap);
        half8 v1 = *(const half8*)(ap + 8);
        *(half8*)&As[0][wo0] = v0;
        *(half8*)&As[0][wo1] = v1;
    }
    pa0 = *(const half8*)(ap + 64);  pa1 = *(const half8*)(ap + 72);
    pb0 = *(const half8*)(ap + 128); pb1 = *(const half8*)(ap + 136);
#pragma unroll
    for (int ks = 0; ks < 2; ++ks)
#pragma unroll
        for (int nf = 0; nf < NFR; ++nf)
            bcur[ks][nf] = *(const half8*)(bp[nf] + ks * 32);

    for (int it = 0; it < NIT; it += 2) {
        __syncthreads();
        if (it + 1 < NIT) {
#pragma unroll
            for (int ks = 0; ks < 2; ++ks)
#pragma unroll
                for (int nf = 0; nf < NFR; ++nf)
                    bnxt[ks][nf] = *(const half8*)(bp[nf] + (it + 1) * 64 + ks * 32);
        }
#pragma unroll
        for (int ks = 0; ks < 2; ++ks) {
            half8 af[4];
#pragma unroll
            for (int mf = 0; mf < 4; ++mf)
                af[mf] = *(const half8*)&As[0][(mf * 16 + lr) * 64 + (((ks * 4 + lg) ^ (lr & 7)) * 8)];
#pragma unroll
            for (int mf = 0; mf < 4; ++mf)
#pragma unroll
                for (int nf = 0; nf < NFR; ++nf)
                    acc[mf][nf] = __builtin_amdgcn_mfma_f32_16x16x32_f16(af[mf], bcur[ks][nf], acc[mf][nf], 0, 0, 0);
        }
        if (it + 1 < NIT) { *(half8*)&As[1][wo0] = pa0; *(half8*)&As[1][wo1] = pa1; }
        if (it + 3 < NIT) { pa0 = *(const half8*)(ap + (it + 3) * 64); pa1 = *(const half8*)(ap + (it + 3) * 64 + 8); }
        if (it + 1 >= NIT) break;

        __syncthreads();
        if (it + 2 < NIT) {
#pragma unroll
            for (int ks = 0; ks < 2; ++ks)
#pragma unroll
                for (int nf = 0; nf < NFR; ++nf)
                    bcur[ks][nf] = *(const half8*)(bp[nf] + (it + 2) * 64 + ks * 32);
        }
#pragma unroll
        for (int ks = 0; ks < 2; ++ks) {
            half8 af[4];
#pragma unroll
            for (int mf = 0; mf < 4; ++mf)
                af[mf] = *(const half8*)&As[1][(mf * 16 + lr) * 64 + (((ks * 4 + lg) ^ (lr & 7)) * 8)];
#pragma unroll
            for (int mf = 0; mf < 4; ++mf)
#pragma unroll
                for (int nf = 0; nf < NFR; ++nf)
                    acc[mf][nf] = __builtin_amdgcn_mfma_f32_16x16x32_f16(af[mf], bnxt[ks][nf], acc[mf][nf], 0, 0, 0);
        }
        if (it + 2 < NIT) { *(half8*)&As[0][wo0] = pb0; *(half8*)&As[0][wo1] = pb1; }
        if (it + 4 < NIT) { pb0 = *(const half8*)(ap + (it + 4) * 64); pb1 = *(const half8*)(ap + (it + 4) * 64 + 8); }
    }

    // H3 tile -> LDS (relu + bias), then head
#pragma unroll
    for (int nf = 0; nf < NFR; ++nf) {
        int col = wv * 32 + nf * 16 + lr;
        float bs = b3[col];
#pragma unroll
        for (int mf = 0; mf < 4; ++mf)
#pragma unroll
            for (int r = 0; r < 4; ++r)
                Hs[mf * 16 + lg * 4 + r][col] = fmaxf(acc[mf][nf][r] + bs, 0.f);
    }
    __syncthreads();

    const int row = tid >> 2, q = tid & 3;
    float a0 = 0.f, a1 = 0.f, a2 = 0.f;
#pragma unroll
    for (int k = 0; k < 32; ++k) {
        float hv = Hs[row][q * 32 + k];
        a0 = fmaf(hv, W4s[(q * 32 + k) * 3 + 0], a0);
        a1 = fmaf(hv, W4s[(q * 32 + k) * 3 + 1], a1);
        a2 = fmaf(hv, W4s[(q * 32 + k) * 3 + 2], a2);
    }
    a0 += __shfl_xor(a0, 1); a0 += __shfl_xor(a0, 2);
    a1 += __shfl_xor(a1, 1); a1 += __shfl_xor(a1, 2);
    a2 += __shfl_xor(a2, 1); a2 += __shfl_xor(a2, 2);
    if (q == 0) {
        const int i = row0 + row;                    // permuted row
        const int b = i >> 12, c = (i >> 9) & 7, s = i & 511;
        const int t = (b << 12) + (s << 3) + c;
        float* o = out + (size_t)t * 3;
        o[0] = a0 + b4[0]; o[1] = a1 + b4[1]; o[2] = a2 + b4[2];
    }
}

extern "C" void kernel_launch(void* const* d_in, const int* in_sizes, int n_in,
                              void* d_out, int out_size, void* d_ws, size_t ws_size,
                              hipStream_t stream) {
    (void)in_sizes; (void)n_in; (void)out_size; (void)ws_size;
    const float* x  = (const float*)d_in[0];
    const float* W1 = (const float*)d_in[1];
    const float* b1 = (const float*)d_in[2];
    const float* W2 = (const float*)d_in[3];
    const float* b2 = (const float*)d_in[4];
    const float* W3 = (const float*)d_in[5];
    const float* b3 = (const float*)d_in[6];
    const float* W4 = (const float*)d_in[7];
    const float* b4 = (const float*)d_in[8];
    float* out = (float*)d_out;

    // ws layout (bytes), total ~92 MB, no aliasing
    char* w = (char*)d_ws;
    half_t* H0    = (half_t*)(w);                                  // 64 MB
    half_t* H1    = (half_t*)(w + (size_t)64 * 1024 * 1024);       // 8 MB
    half_t* H2    = (half_t*)(w + (size_t)72 * 1024 * 1024);       // 8 MB
    half_t* W1T   = (half_t*)(w + (size_t)88 * 1024 * 1024);       // 1 MB
    half_t* W2T   = (half_t*)(w + (size_t)89 * 1024 * 1024);       // 128 KB
    half_t* W3T   = W2T + 256 * 256;                               // 64 KB
    half_t* dftH  = W3T + 128 * 256;                               // 8 KB
    half_t* lineG = (half_t*)(w + (size_t)90 * 1024 * 1024);       // 2 MB

    prep_kernel<<<2448, 256, 0, stream>>>(W1, W2, W3, dftH, W1T, W2T, W3T);
    xr_kernel<<<304, 256, 0, stream>>>(x, lineG, H0);
    fft_hankel<<<240 * 8, 256, 0, stream>>>(lineG, dftH, H0);

    // GEMM1: [16384,2048] x [2048,256], BN=64 -> grid (256,4) = 1024 blocks
    gemm_pipe<64><<<dim3(NTOK / 64, 4), 256, 0, stream>>>(
        H0, KPAD, W1T, KPAD, b1, H1, HID, KPAD);
    // GEMM2: [16384,256] x [256,256], 1024 blocks
    gemm_pipe<64><<<dim3(NTOK / 64, 4), 256, 0, stream>>>(
        H1, HID, W2T, HID, b2, H2, HID, HID);
    // GEMM3 + head fused
    gemm3_head<<<NTOK / 64, 256, 0, stream>>>(H2, W3T, b3, W4, b4, out);
}

// Round 17
// 101.914 us; speedup vs baseline: 1.0647x; 1.0647x over previous
//
#include <hip/hip_runtime.h>
#include <math.h>

#define T_LEN 4096
#define NF 60
#define NBINS 33
#define KPAD 2048
#define HID 256
#define NTOK 16384
#define LINE 4208    // reflected line length (covers staging slop, mult of 8)

typedef _Float16 half_t;
typedef half_t half8 __attribute__((ext_vector_type(8)));
typedef half_t half4 __attribute__((ext_vector_type(4)));
typedef float f32x4 __attribute__((ext_vector_type(4)));

// ---------- compile-time cos table: cos(2*pi*j/64), j=0..63 ----------
constexpr double K_PI = 3.14159265358979323846;
constexpr double tcos(double x) {
    while (x >  K_PI) x -= 2.0 * K_PI;
    while (x < -K_PI) x += 2.0 * K_PI;
    double x2 = x * x, s = 0.0, term = 1.0;
    for (int m = 0; m < 14; ++m) { s += term; term *= -x2 / ((2.0*m + 1.0) * (2.0*m + 2.0)); }
    return s;
}
struct CosTab { float v[64]; };
constexpr CosTab make_tab() {
    CosTab t{};
    for (int j = 0; j < 64; ++j) t.v[j] = (float)tcos(2.0 * K_PI * (double)j / 64.0);
    return t;
}
__device__ constexpr CosTab CTd = make_tab();

// stored fft feature = log2(1+mag); the *ln2 is folded into W1T rows.
__device__ __forceinline__ float log2_1p(float x) {
    return __log2f(1.0f + x);
}

// ---------- one-time prep: fp16 DFT table + fp16 transposed weights ----------
// k-layout: [0,1920) bins (f=k>>5, bin=k&31); [1920,1980) raw; [1980,2040)
// bin32 of f=k-1980; [2040,2048) zero.  FFT-feature rows scaled by ln2.
__global__ __launch_bounds__(256) void prep_kernel(
        const float* __restrict__ W1, const float* __restrict__ W2,
        const float* __restrict__ W3,
        half_t* __restrict__ dftH,
        half_t* __restrict__ W1T, half_t* __restrict__ W2T,
        half_t* __restrict__ W3T) {
    int i = blockIdx.x * 256 + threadIdx.x;
    if (i < 4096) {
        int row = i >> 6, n = i & 63;
        float c = (row < 33) ? CTd.v[(row * n) & 63]
                             : CTd.v[((row - 32) * n + 48) & 63];
        dftH[i] = (half_t)c;
        return;
    }
    i -= 4096;
    if (i < 256 * KPAD) {
        int gk = i & (KPAD - 1);
        float v = 0.f;
        if (gk < 2040) {
            int j = i >> 11;
            int r;
            bool isfft = true;
            if (gk < 1920) {
                int f = gk >> 5, bin = gk & 31;
                r = NF + f * NBINS + bin;                 // bins 0..31
            } else if (gk < 1980) {
                r = gk - 1920; isfft = false;             // raw feature
            } else {
                r = NF + (gk - 1980) * NBINS + 32;        // bin 32
            }
            v = W1[(size_t)r * HID + j];
            if (isfft) v *= 0.69314718055994531f;         // ln2 fold
        }
        W1T[i] = (half_t)v;
        return;
    }
    i -= 256 * KPAD;
    if (i < 256 * 256) {
        int k = i & 255, j = i >> 8;
        W2T[i] = (half_t)W2[(size_t)k * HID + j];
        return;
    }
    i -= 256 * 256;
    if (i < 128 * 256) {
        int k = i & 255, j = i >> 8;
        W3T[i] = (half_t)W3[(size_t)k * 128 + j];
    }
}

// ---------- merged: reflected lines (blocks 0..239) + raw feats (240..303) --
__global__ __launch_bounds__(256) void xr_kernel(
        const float* __restrict__ x, half_t* __restrict__ lineG,
        half_t* __restrict__ H0) {
    if (blockIdx.x < 240) {
        const int bf = blockIdx.x;
        const int b = bf / NF, f = bf - b * NF;
        const float* xb = x + (size_t)b * T_LEN * NF + f;
        half_t* L = lineG + (size_t)bf * LINE;
        for (int j = threadIdx.x; j < LINE; j += 256) {
            int s = j - 32;
            int r = (s < 0) ? -s : ((s > T_LEN - 1) ? 2 * (T_LEN - 1) - s : s);
            L[j] = (half_t)xb[(size_t)r * NF];
        }
        return;
    }
    const int t = (blockIdx.x - 240) * 256 + threadIdx.x;
    const int b = t >> 12, tl = t & (T_LEN - 1);
    const int i = (b << 12) + ((tl & 7) << 9) + (tl >> 3);
    const float* xp = x + (size_t)t * NF;
    half_t* hp = H0 + (size_t)i * KPAD;
#pragma unroll
    for (int f4 = 0; f4 < 15; ++f4) {
        float4 v = *(const float4*)(xp + f4 * 4);
        half4 h;
        h[0] = (half_t)v.x; h[1] = (half_t)v.y;
        h[2] = (half_t)v.z; h[3] = (half_t)v.w;
        *(half4*)&hp[1920 + f4 * 4] = h;
    }
    half8 z = {};
    *(half8*)&hp[2040] = z;
}

// ---------- Hankel-DFT via MFMA: block = (b,f,phase c); ILP-pipelined ------
// Epilogue v2: per-wave LDS transpose tile -> one full 64B line per token
// (100% write-line efficiency, half the global store instructions).
__global__ __launch_bounds__(256) void fft_hankel(
        const half_t* __restrict__ lineG, const half_t* __restrict__ dftH,
        half_t* __restrict__ H0) {
    __shared__ half_t L[4160];         // full c-shifted line (8.3 KB)
    __shared__ half_t Tt[4][16 * 36];  // per-wave 16 tok x 32 bins (stride 36)

    const int bid = blockIdx.x;        // 0..1919
    const int bf = bid >> 3, c = bid & 7;
    const int b = bf / NF, f = bf - b * NF;
    const int tid = threadIdx.x;
    const int lane = tid & 63, wv = tid >> 6;
    const int lr = lane & 15, lg = lane >> 4;

    half8 a[4][2];
#pragma unroll
    for (int rf = 0; rf < 4; ++rf)
#pragma unroll
        for (int ks = 0; ks < 2; ++ks)
            a[rf][ks] = *(const half8*)&dftH[(16 * rf + lr) * 64 + ks * 32 + lg * 8];

    {
        const half_t* src = lineG + (size_t)bf * LINE + c;
        for (int j = tid; j < 4152; j += 256) L[j] = src[j];
    }
    __syncthreads();

    const int i0 = (b << 12) + (c << 9);    // H0 row base
    const int sl = wv * 128 + lr;           // this thread's s for cs=0
    const int tl = lane >> 2, q = lane & 3; // readback lane mapping

    half8 w0 = *(const half8*)&L[8 * sl + lg * 8];
    half8 w1 = *(const half8*)&L[8 * sl + 32 + lg * 8];

#pragma unroll
    for (int cs = 0; cs < 8; ++cs) {
        f32x4 dacc[4] = {};
#pragma unroll
        for (int rf = 0; rf < 4; ++rf)
            dacc[rf] = __builtin_amdgcn_mfma_f32_16x16x32_f16(a[rf][0], w0, dacc[rf], 0, 0, 0);
#pragma unroll
        for (int rf = 0; rf < 4; ++rf)
            dacc[rf] = __builtin_amdgcn_mfma_f32_16x16x32_f16(a[rf][1], w1, dacc[rf], 0, 0, 0);

        if (cs < 7) {   // prefetch next chunk's B-frags (hidden under epilogue)
            const int sn = sl + (cs + 1) * 16;
            w0 = *(const half8*)&L[8 * sn + lg * 8];
            w1 = *(const half8*)&L[8 * sn + 32 + lg * 8];
        }

        // epilogue: rf0=re0..15, rf1=re16..31, rf2=row32(re32)+im1..15, rf3=im16..31
        // 1) mag/log -> per-wave LDS tile (token-major, stride 36 halfs)
#pragma unroll
        for (int rf = 0; rf < 2; ++rf) {
            half4 h4;
#pragma unroll
            for (int r = 0; r < 4; ++r) {
                float re = dacc[rf][r];
                float im = dacc[rf + 2][r];
                float v = (rf == 0 && r == 0)
                    ? ((lg == 0) ? log2_1p(fabsf(re))                 // bin 0
                                 : log2_1p(sqrtf(re * re + im * im)))
                    : log2_1p(sqrtf(re * re + im * im));
                h4[r] = (half_t)v;
            }
            *(half4*)&Tt[wv][lr * 36 + rf * 16 + lg * 4] = h4;
        }
        asm volatile("s_waitcnt lgkmcnt(0)" ::: "memory");
        // 2) readback 16B/lane, 4 lanes per token -> one 64B line per row
        {
            half8 rowv = *(const half8*)&Tt[wv][tl * 36 + q * 8];
            const int gtok = i0 + wv * 128 + cs * 16 + tl;
            *(half8*)&H0[(size_t)gtok * KPAD + f * 32 + q * 8] = rowv;
        }
        if (lg == 0)   // bin 32 = |re_32| (row 32 = rf2 reg0)
            H0[(size_t)(i0 + sl + cs * 16) * KPAD + 1980 + f] =
                (half_t)log2_1p(fabsf(dacc[2][0]));
    }
}

// ---------- fp16 MFMA GEMM, software-pipelined (layers 1,2) ----------
// BM=64. A: LDS dbuf, 3-deep reg prefetch, XOR-swizzled granules (<=2-way).
// B: direct from L2, 2-deep reg double-buffer. ONE barrier per K-step.
template<int BN>
__global__ __launch_bounds__(256, 2) void gemm_pipe(
        const half_t* __restrict__ A, int lda,
        const half_t* __restrict__ BT, int ldb,
        const float* __restrict__ bias,
        half_t* __restrict__ Ch, int N, int K) {
    constexpr int NFR = BN / 64;
    __shared__ half_t As[2][64 * 64];     // 16 KB, swizzled granules

    const int tid  = threadIdx.x;
    const int row0 = blockIdx.x * 64;
    const int col0 = blockIdx.y * BN;
    const int wv = tid >> 6, lane = tid & 63;
    const int lr = lane & 15, lg = lane >> 4;

    const int srow = tid >> 2, sg = (tid & 3) * 2;
    const int wo0 = srow * 64 + ((sg ^ (srow & 7)) * 8);
    const int wo1 = srow * 64 + (((sg + 1) ^ (srow & 7)) * 8);
    const half_t* ap = A + (size_t)(row0 + srow) * lda + sg * 8;

    const half_t* bp[NFR];
#pragma unroll
    for (int nf = 0; nf < NFR; ++nf)
        bp[nf] = BT + (size_t)(col0 + wv * (16 * NFR) + nf * 16 + lr) * ldb + lg * 8;

    f32x4 acc[4][NFR] = {};
    const int NIT = K / 64;   // even

    half8 bcur[2][NFR], bnxt[2][NFR];
    half8 pa0, pa1, pb0, pb1;

    {
        half8 v0 = *(const half8*)(ap);
        half8 v1 = *(const half8*)(ap + 8);
        *(half8*)&As[0][wo0] = v0;
        *(half8*)&As[0][wo1] = v1;
    }
    if (NIT > 1) { pa0 = *(const half8*)(ap + 64);  pa1 = *(const half8*)(ap + 72); }
    if (NIT > 2) { pb0 = *(const half8*)(ap + 128); pb1 = *(const half8*)(ap + 136); }
#pragma unroll
    for (int ks = 0; ks < 2; ++ks)
#pragma unroll
        for (int nf = 0; nf < NFR; ++nf)
            bcur[ks][nf] = *(const half8*)(bp[nf] + ks * 32);

    for (int it = 0; it < NIT; it += 2) {
        __syncthreads();
        if (it + 1 < NIT) {
#pragma unroll
            for (int ks = 0; ks < 2; ++ks)
#pragma unroll
                for (int nf = 0; nf < NFR; ++nf)
                    bnxt[ks][nf] = *(const half8*)(bp[nf] + (it + 1) * 64 + ks * 32);
        }
#pragma unroll
        for (int ks = 0; ks < 2; ++ks) {
            half8 af[4];
#pragma unroll
            for (int mf = 0; mf < 4; ++mf)
                af[mf] = *(const half8*)&As[0][(mf * 16 + lr) * 64 + (((ks * 4 + lg) ^ (lr & 7)) * 8)];
#pragma unroll
            for (int mf = 0; mf < 4; ++mf)
#pragma unroll
                for (int nf = 0; nf < NFR; ++nf)
                    acc[mf][nf] = __builtin_amdgcn_mfma_f32_16x16x32_f16(af[mf], bcur[ks][nf], acc[mf][nf], 0, 0, 0);
        }
        if (it + 1 < NIT) { *(half8*)&As[1][wo0] = pa0; *(half8*)&As[1][wo1] = pa1; }
        if (it + 3 < NIT) { pa0 = *(const half8*)(ap + (it + 3) * 64); pa1 = *(const half8*)(ap + (it + 3) * 64 + 8); }
        if (it + 1 >= NIT) break;

        __syncthreads();
        if (it + 2 < NIT) {
#pragma unroll
            for (int ks = 0; ks < 2; ++ks)
#pragma unroll
                for (int nf = 0; nf < NFR; ++nf)
                    bcur[ks][nf] = *(const half8*)(bp[nf] + (it + 2) * 64 + ks * 32);
        }
#pragma unroll
        for (int ks = 0; ks < 2; ++ks) {
            half8 af[4];
#pragma unroll
            for (int mf = 0; mf < 4; ++mf)
                af[mf] = *(const half8*)&As[1][(mf * 16 + lr) * 64 + (((ks * 4 + lg) ^ (lr & 7)) * 8)];
#pragma unroll
            for (int mf = 0; mf < 4; ++mf)
#pragma unroll
                for (int nf = 0; nf < NFR; ++nf)
                    acc[mf][nf] = __builtin_amdgcn_mfma_f32_16x16x32_f16(af[mf], bnxt[ks][nf], acc[mf][nf], 0, 0, 0);
        }
        if (it + 2 < NIT) { *(half8*)&As[0][wo0] = pb0; *(half8*)&As[0][wo1] = pb1; }
        if (it + 4 < NIT) { pb0 = *(const half8*)(ap + (it + 4) * 64); pb1 = *(const half8*)(ap + (it + 4) * 64 + 8); }
    }

#pragma unroll
    for (int nf = 0; nf < NFR; ++nf) {
        int col = col0 + wv * (16 * NFR) + nf * 16 + lr;
        float bs = bias[col];
#pragma unroll
        for (int mf = 0; mf < 4; ++mf)
#pragma unroll
            for (int r = 0; r < 4; ++r) {
                int row = row0 + mf * 16 + lg * 4 + r;
                Ch[(size_t)row * N + col] = (half_t)fmaxf(acc[mf][nf][r] + bs, 0.f);
            }
    }
}

// ---------- GEMM3 + head fused: H2[64rows] @ W3 -> LDS -> @ W4 -> out ------
__global__ __launch_bounds__(256) void gemm3_head(
        const half_t* __restrict__ A, const half_t* __restrict__ BT,
        const float* __restrict__ b3, const float* __restrict__ W4,
        const float* __restrict__ b4, float* __restrict__ out) {
    constexpr int NFR = 2, NIT = 4;
    __shared__ half_t As[2][64 * 64];     // 16 KB
    __shared__ float Hs[64][132];         // 33.8 KB (pad 4)
    __shared__ float W4s[384];

    const int tid  = threadIdx.x;
    const int row0 = blockIdx.x * 64;
    const int wv = tid >> 6, lane = tid & 63;
    const int lr = lane & 15, lg = lane >> 4;

    for (int i = tid; i < 384; i += 256) W4s[i] = W4[i];

    const int srow = tid >> 2, sg = (tid & 3) * 2;
    const int wo0 = srow * 64 + ((sg ^ (srow & 7)) * 8);
    const int wo1 = srow * 64 + (((sg + 1) ^ (srow & 7)) * 8);
    const half_t* ap = A + (size_t)(row0 + srow) * 256 + sg * 8;

    const half_t* bp[NFR];
#pragma unroll
    for (int nf = 0; nf < NFR; ++nf)
        bp[nf] = BT + (size_t)(wv * 32 + nf * 16 + lr) * 256 + lg * 8;

    f32x4 acc[4][NFR] = {};
    half8 bcur[2][NFR], bnxt[2][NFR];
    half8 pa0, pa1, pb0, pb1;

    {
        half8 v0 = *(const half8*)(ap);
        half8 v1 = *(const half8*)(ap + 8);
        *(half8*)&As[0][wo0] = v0;
        *(half8*)&As[0][wo1] = v1;
    }
    pa0 = *(const half8*)(ap + 64);  pa1 = *(const half8*)(ap + 72);
    pb0 = *(const half8*)(ap + 128); pb1 = *(const half8*)(ap + 136);
#pragma unroll
    for (int ks = 0; ks < 2; ++ks)
#pragma unroll
        for (int nf = 0; nf < NFR; ++nf)
            bcur[ks][nf] = *(const half8*)(bp[nf] + ks * 32);

    for (int it = 0; it < NIT; it += 2) {
        __syncthreads();
        if (it + 1 < NIT) {
#pragma unroll
            for (int ks = 0; ks < 2; ++ks)
#pragma unroll
                for (int nf = 0; nf < NFR; ++nf)
                    bnxt[ks][nf] = *(const half8*)(bp[nf] + (it + 1) * 64 + ks * 32);
        }
#pragma unroll
        for (int ks = 0; ks < 2; ++ks) {
            half8 af[4];
#pragma unroll
            for (int mf = 0; mf < 4; ++mf)
                af[mf] = *(const half8*)&As[0][(mf * 16 + lr) * 64 + (((ks * 4 + lg) ^ (lr & 7)) * 8)];
#pragma unroll
            for (int mf = 0; mf < 4; ++mf)
#pragma unroll
                for (int nf = 0; nf < NFR; ++nf)
                    acc[mf][nf] = __builtin_amdgcn_mfma_f32_16x16x32_f16(af[mf], bcur[ks][nf], acc[mf][nf], 0, 0, 0);
        }
        if (it + 1 < NIT) { *(half8*)&As[1][wo0] = pa0; *(half8*)&As[1][wo1] = pa1; }
        if (it + 3 < NIT) { pa0 = *(const half8*)(ap + (it + 3) * 64); pa1 = *(const half8*)(ap + (it + 3) * 64 + 8); }
        if (it + 1 >= NIT) break;

        __syncthreads();
        if (it + 2 < NIT) {
#pragma unroll
            for (int ks = 0; ks < 2; ++ks)
#pragma unroll
                for (int nf = 0; nf < NFR; ++nf)
                    bcur[ks][nf] = *(const half8*)(bp[nf] + (it + 2) * 64 + ks * 32);
        }
#pragma unroll
        for (int ks = 0; ks < 2; ++ks) {
            half8 af[4];
#pragma unroll
            for (int mf = 0; mf < 4; ++mf)
                af[mf] = *(const half8*)&As[1][(mf * 16 + lr) * 64 + (((ks * 4 + lg) ^ (lr & 7)) * 8)];
#pragma unroll
            for (int mf = 0; mf < 4; ++mf)
#pragma unroll
                for (int nf = 0; nf < NFR; ++nf)
                    acc[mf][nf] = __builtin_amdgcn_mfma_f32_16x16x32_f16(af[mf], bnxt[ks][nf], acc[mf][nf], 0, 0, 0);
        }
        if (it + 2 < NIT) { *(half8*)&As[0][wo0] = pb0; *(half8*)&As[0][wo1] = pb1; }
        if (it + 4 < NIT) { pb0 = *(const half8*)(ap + (it + 4) * 64); pb1 = *(const half8*)(ap + (it + 4) * 64 + 8); }
    }

    // H3 tile -> LDS (relu + bias), then head
#pragma unroll
    for (int nf = 0; nf < NFR; ++nf) {
        int col = wv * 32 + nf * 16 + lr;
        float bs = b3[col];
#pragma unroll
        for (int mf = 0; mf < 4; ++mf)
#pragma unroll
            for (int r = 0; r < 4; ++r)
                Hs[mf * 16 + lg * 4 + r][col] = fmaxf(acc[mf][nf][r] + bs, 0.f);
    }
    __syncthreads();

    const int row = tid >> 2, q = tid & 3;
    float a0 = 0.f, a1 = 0.f, a2 = 0.f;
#pragma unroll
    for (int k = 0; k < 32; ++k) {
        float hv = Hs[row][q * 32 + k];
        a0 = fmaf(hv, W4s[(q * 32 + k) * 3 + 0], a0);
        a1 = fmaf(hv, W4s[(q * 32 + k) * 3 + 1], a1);
        a2 = fmaf(hv, W4s[(q * 32 + k) * 3 + 2], a2);
    }
    a0 += __shfl_xor(a0, 1); a0 += __shfl_xor(a0, 2);
    a1 += __shfl_xor(a1, 1); a1 += __shfl_xor(a1, 2);
    a2 += __shfl_xor(a2, 1); a2 += __shfl_xor(a2, 2);
    if (q == 0) {
        const int i = row0 + row;                    // permuted row
        const int b = i >> 12, c = (i >> 9) & 7, s = i & 511;
        const int t = (b << 12) + (s << 3) + c;
        float* o = out + (size_t)t * 3;
        o[0] = a0 + b4[0]; o[1] = a1 + b4[1]; o[2] = a2 + b4[2];
    }
}

extern "C" void kernel_launch(void* const* d_in, const int* in_sizes, int n_in,
                              void* d_out, int out_size, void* d_ws, size_t ws_size,
                              hipStream_t stream) {
    (void)in_sizes; (void)n_in; (void)out_size; (void)ws_size;
    const float* x  = (const float*)d_in[0];
    const float* W1 = (const float*)d_in[1];
    const float* b1 = (const float*)d_in[2];
    const float* W2 = (const float*)d_in[3];
    const float* b2 = (const float*)d_in[4];
    const float* W3 = (const float*)d_in[5];
    const float* b3 = (const float*)d_in[6];
    const float* W4 = (const float*)d_in[7];
    const float* b4 = (const float*)d_in[8];
    float* out = (float*)d_out;

    // ws layout (bytes), total ~92 MB, no aliasing
    char* w = (char*)d_ws;
    half_t* H0    = (half_t*)(w);                                  // 64 MB
    half_t* H1    = (half_t*)(w + (size_t)64 * 1024 * 1024);       // 8 MB
    half_t* H2    = (half_t*)(w + (size_t)72 * 1024 * 1024);       // 8 MB
    half_t* W1T   = (half_t*)(w + (size_t)88 * 1024 * 1024);       // 1 MB
    half_t* W2T   = (half_t*)(w + (size_t)89 * 1024 * 1024);       // 128 KB
    half_t* W3T   = W2T + 256 * 256;                               // 64 KB
    half_t* dftH  = W3T + 128 * 256;                               // 8 KB
    half_t* lineG = (half_t*)(w + (size_t)90 * 1024 * 1024);       // 2 MB

    prep_kernel<<<2448, 256, 0, stream>>>(W1, W2, W3, dftH, W1T, W2T, W3T);
    xr_kernel<<<304, 256, 0, stream>>>(x, lineG, H0);
    fft_hankel<<<240 * 8, 256, 0, stream>>>(lineG, dftH, H0);

    // GEMM1: [16384,2048] x [2048,256], BN=128, grid (256,2) (min-A-traffic)
    gemm_pipe<128><<<dim3(NTOK / 64, 2), 256, 0, stream>>>(
        H0, KPAD, W1T, KPAD, b1, H1, HID, KPAD);
    // GEMM2: [16384,256] x [256,256]
    gemm_pipe<128><<<dim3(NTOK / 64, 2), 256, 0, stream>>>(
        H1, HID, W2T, HID, b2, H2, HID, HID);
    // GEMM3 + head fused
    gemm3_head<<<NTOK / 64, 256, 0, stream>>>(H2, W3T, b3, W4, b4, out);
}